// Round 14
// baseline (382.677 us; speedup 1.0000x reference)
//
#include <hip/hip_runtime.h>
#include <stdint.h>
#include <math.h>

#define NOISE_LEVEL 0.02f
#define CROSSTALK   0.05f
#define COHERENCE   0.03f
// coherence factor with E[n^2]=1: 1 + 0.03*(exp(-0.03^2/2)-1) = 1 - 1.3497e-5
#define F_COH 0.99998650f

typedef _Float16 half8 __attribute__((ext_vector_type(8)));
typedef _Float16 half4 __attribute__((ext_vector_type(4)));
typedef __attribute__((ext_vector_type(4))) float f32x4;

#define TF_ROUND(x0,x1,R) { x0 += x1; x1 = ((x1 << (R)) | (x1 >> (32-(R)))); x1 ^= x0; }

__host__ __device__ inline void threefry2x32(uint32_t k0, uint32_t k1,
                                             uint32_t x0, uint32_t x1,
                                             uint32_t& o0, uint32_t& o1)
{
  uint32_t ks2 = k0 ^ k1 ^ 0x1BD11BDAu;
  x0 += k0; x1 += k1;
  TF_ROUND(x0,x1,13) TF_ROUND(x0,x1,15) TF_ROUND(x0,x1,26) TF_ROUND(x0,x1,6)
  x0 += k1; x1 += ks2 + 1u;
  TF_ROUND(x0,x1,17) TF_ROUND(x0,x1,29) TF_ROUND(x0,x1,16) TF_ROUND(x0,x1,24)
  x0 += ks2; x1 += k0 + 2u;
  TF_ROUND(x0,x1,13) TF_ROUND(x0,x1,15) TF_ROUND(x0,x1,26) TF_ROUND(x0,x1,6)
  x0 += k0; x1 += k1 + 3u;
  TF_ROUND(x0,x1,17) TF_ROUND(x0,x1,29) TF_ROUND(x0,x1,16) TF_ROUND(x0,x1,24)
  x0 += k1; x1 += ks2 + 4u;
  TF_ROUND(x0,x1,13) TF_ROUND(x0,x1,15) TF_ROUND(x0,x1,26) TF_ROUND(x0,x1,6)
  o0 = x0 + ks2; o1 = x1 + k0 + 5u;
}

// threefry_partitionable bits for 32-bit draws: XOR of the two output words.
__device__ inline uint32_t jax_bits(uint32_t k0, uint32_t k1, uint32_t idx)
{
  uint32_t o0, o1; threefry2x32(k0, k1, 0u, idx, o0, o1); return o0 ^ o1;
}

// JAX random.normal(float32): u ~ uniform[-0.99999994, 1); n = sqrt(2)*erfinv(u)
__device__ inline float jax_normal(uint32_t k0, uint32_t k1, uint32_t idx)
{
  uint32_t bits = jax_bits(k0, k1, idx);
  float f = __uint_as_float((bits >> 9) | 0x3f800000u) - 1.0f;   // [0,1)
  float u = fmaf(f, 2.0f, -0.99999994f);
  u = fmaxf(-0.99999994f, u);
  float w = -__logf(fmaf(-u, u, 1.0f));
  float wl = w - 2.5f;
  float p = 2.81022636e-08f;
  p = fmaf(p, wl, 3.43273939e-07f);
  p = fmaf(p, wl, -3.5233877e-06f);
  p = fmaf(p, wl, -4.39150654e-06f);
  p = fmaf(p, wl, 0.00021858087f);
  p = fmaf(p, wl, -0.00125372503f);
  p = fmaf(p, wl, -0.00417768164f);
  p = fmaf(p, wl, 0.246640727f);
  p = fmaf(p, wl, 1.50140941f);
  if (__any(w >= 5.0f)) {
    float ws = sqrtf(w) - 3.0f;
    float q = -0.000200214257f;
    q = fmaf(q, ws, 0.000100950558f);
    q = fmaf(q, ws, 0.00134934322f);
    q = fmaf(q, ws, -0.00367342844f);
    q = fmaf(q, ws, 0.00573950773f);
    q = fmaf(q, ws, -0.0076224613f);
    q = fmaf(q, ws, 0.00943887047f);
    q = fmaf(q, ws, 1.00167406f);
    q = fmaf(q, ws, 2.83297682f);
    p = (w >= 5.0f) ? q : p;
  }
  return 1.41421354f * (p * u);
}

// exact-algebra tanh via fast exp; abs err <= ~1.2e-7, inf-safe.
__device__ inline float tanh_fast(float x)
{
  float ax = fabsf(x);
  float e = __expf(2.0f * ax);
  float r = 1.0f - 2.0f / (e + 1.0f);
  return copysignf(r, x);
}

// ---------------------------------------------------------------------------
// Packed fp16 operand layout (BK=32, row-block RB = 1<<rbbits):
//   tile (rb,kt) occupies RB*32 halves at (rb*ktiles + kt)*RB*32,
//   internally [kq(4)][row(RB)][8].
// A planes: RB=128 (rbbits=7); B/W planes: RB=64 (rbbits=6) = BN.
//
// R14 fix: thread->slot mapping is (kq = s&3, row = s>>2) so 4 consecutive
// threads read one ROW's 32 consecutive floats (128B coalesced), and writes
// form 16-row x 16B = 256B contiguous runs per kq (full lines, no RMW).
// Layout itself is unchanged (GEMM staging untouched).
// ---------------------------------------------------------------------------
__global__ __launch_bounds__(256)
void pack_all(const float* __restrict__ W1, const float* __restrict__ W2,
              const float* __restrict__ x,
              _Float16* __restrict__ W1p, _Float16* __restrict__ W2p,
              _Float16* __restrict__ xpk)
{
  const int n0 = (2048 * 1024) / 8;     // W1 slots
  const int n1 = (2048 * 2048) / 8;     // W2 slots
  const int n2 = (8192 * 1024) / 8;     // x  slots
  const int total = n0 + n1 + n2;
  int g = blockIdx.x * 256 + threadIdx.x;
  const int stride = gridDim.x * 256;
  for (; g < total; g += stride) {
    const float* in; _Float16* out;
    int gg, K, kshift, rbbits, do_tanh;
    if (g < n0)           { in = W1; out = W1p; gg = g;           K = 1024; kshift = 5; rbbits = 6; do_tanh = 0; }
    else if (g < n0 + n1) { in = W2; out = W2p; gg = g - n0;      K = 2048; kshift = 6; rbbits = 6; do_tanh = 0; }
    else                  { in = x;  out = xpk; gg = g - n0 - n1; K = 1024; kshift = 5; rbbits = 7; do_tanh = 1; }
    const int ktm = (K >> 5) - 1;
    const int slotbits = rbbits + 2;
    int tile = gg >> slotbits;
    int s = gg & ((1 << slotbits) - 1);
    int kq = s & 3, row = s >> 2;                 // coalesced-read mapping
    int rb = tile >> kshift, kt = tile & ktm;
    int r = (rb << rbbits) + row;
    int k = kt * 32 + kq * 8;
    const float* src = in + (size_t)r * K + k;
    float4 v0 = *(const float4*)src;
    float4 v1 = *(const float4*)(src + 4);
    float xs[8] = {v0.x, v0.y, v0.z, v0.w, v1.x, v1.y, v1.z, v1.w};
    half8 h;
    #pragma unroll
    for (int e = 0; e < 8; ++e) {
      float xv = do_tanh ? tanh_fast(xs[e]) : xs[e];
      h[e] = (_Float16)xv;
    }
    // layout slot = kq*RB + row (unchanged layout)
    size_t oslot = ((size_t)tile << slotbits) + (kq << rbbits) + row;
    *(half8*)&out[oslot * 8] = h;
  }
}

// bias_fold: fold[j] = b[j] + scale * sum_h tn[h] * W[j,h]  (fp32; one wave/j)
__global__ __launch_bounds__(256)
void bias_fold(const float* __restrict__ tn, const float* __restrict__ W,
               const float* __restrict__ b, float* __restrict__ fold,
               int K, int nrows, float scale)
{
  const int wid = threadIdx.x >> 6;
  const int lane = threadIdx.x & 63;
  const int j = blockIdx.x * 4 + wid;
  if (j >= nrows) return;
  const float* row = W + (size_t)j * K;
  float s = 0.0f;
  for (int h = lane; h < K; h += 64) s = fmaf(tn[h], row[h], s);
  #pragma unroll
  for (int off = 32; off > 0; off >>= 1) s += __shfl_down(s, off);
  if (lane == 0) fold[j] = fmaf(scale, s, b[j]);
}

// ---------------------------------------------------------------------------
// fp16 MFMA GEMM, BM=128 x BN=64, BK=32, 4 waves, R11 double-buffered loop.
//   v = tanh(oscale*acc + bias) + 0.02*normal(key, r*N+c); colabs += sum|v|.
// OUTMODE 0 (G1): epilogue transposes C through XOR-swizzled LDS then stores
//   the block's 64KB in EXACT a1pk packed order (coalesced, no L2 RMW).
// OUTMODE 1 (G2): FUSED FINAL - no global x2 write at all. Per (fm,j) row,
//   dot the lane's 2 cols with Wout rows 0/1, butterfly over lm lanes,
//   atomicAdd F_COH*partial into out[r*2+d]. out pre-zeroed; foldout added
//   by add_fold afterwards. va fp16-rounded exactly like the old a2n store.
// Block order: XCD region 16bm x 16bn in 4bm x 8bn L2 sub-chunks.
// ---------------------------------------------------------------------------
#define BM 128
#define BN 64
#define ATILE 4096            // halves per A tile (128*32)
#define BTILE 2048            // halves per B tile (64*32)
#define BUFH  (ATILE + BTILE)

__device__ __forceinline__ f32x4 noise_group(int g, int blockM, int blockN,
                                             int wr, int wc, int lg, int lm,
                                             int N, uint32_t k0, uint32_t k1)
{
  int fn = g >> 2, fm = g & 3;
  int gr0 = blockM + wr * 64 + fm * 16 + lg * 4;
  int gc  = blockN + wc * 32 + fn * 16 + lm;
  f32x4 r;
  #pragma unroll
  for (int j = 0; j < 4; ++j)
    r[j] = jax_normal(k0, k1, (uint32_t)((gr0 + j) * N + gc));
  return r;
}

template<int OUTMODE>
__global__ __launch_bounds__(256, 5)
void gemm_f16(const _Float16* __restrict__ Ap, const _Float16* __restrict__ Bp,
              const float* __restrict__ bias, _Float16* __restrict__ outn,
              float* __restrict__ colabs,
              const float* __restrict__ Wout, float* __restrict__ outf,
              int M, int N, int K, float oscale,
              uint32_t nk0, uint32_t nk1)
{
  __shared__ __align__(16) _Float16 lds[2 * BUFH];   // 24 KiB

  const int t = threadIdx.x;
  // XCD-region + L2-sub-chunk block order (grid = 64bm x 32bn, 8 XCDs)
  const int bid = blockIdx.x;
  const int xcd = bid & 7, p = bid >> 3;       // p in [0,256) per XCD
  const int s = p >> 5, q = p & 31;            // 8 sub-chunks of 32 blocks
  const int bm = ((xcd >> 1) << 4) + ((s >> 1) << 2) + (q >> 3);
  const int bn = ((xcd & 1) << 4) + ((s & 1) << 3) + (q & 7);
  const int blockM = bm * BM, blockN = bn * BN;

  const int lane = t & 63;
  const int w = t >> 6;
  const int wr = w >> 1, wc = w & 1;
  const int lm = lane & 15, lg = lane >> 4;

  const int ktiles = K >> 5;

  // staging: 12 x 1KB global_load_lds per k-tile; wave w issues loads 3w..3w+2
  const _Float16* gsrc[3];
  int gstride[3];
  _Float16* ldst[3];
  #pragma unroll
  for (int i = 0; i < 3; ++i) {
    int l = w * 3 + i;
    if (l < 8) {
      gsrc[i] = Ap + ((size_t)bm * ktiles) * ATILE + l * 512 + lane * 8;
      gstride[i] = ATILE;
      ldst[i] = lds + l * 512;
    } else {
      gsrc[i] = Bp + ((size_t)bn * ktiles) * BTILE + (l - 8) * 512 + lane * 8;
      gstride[i] = BTILE;
      ldst[i] = lds + ATILE + (l - 8) * 512;
    }
  }

#define STAGE(buf, kt_) {                                                      \
    _Pragma("unroll")                                                          \
    for (int i = 0; i < 3; ++i)                                                \
      __builtin_amdgcn_global_load_lds(                                        \
          (const void*)(gsrc[i] + (size_t)(kt_) * gstride[i]),                 \
          (void*)(ldst[i] + (buf) * BUFH), 16, 0, 0);                          \
  }

  f32x4 acc[4][2];
  #pragma unroll
  for (int i = 0; i < 4; ++i)
    #pragma unroll
    for (int j = 0; j < 2; ++j) acc[i][j] = 0.0f;

  half4 nh0 = 0, nh1 = 0, nh2 = 0, nh3 = 0, nh4 = 0, nh5 = 0, nh6 = 0, nh7 = 0;

  const int nk = ktiles;               // 32 (G1) or 64 (G2)
  STAGE(0, 0);
  __syncthreads();
  int cur = 0;

  for (int kt = 0; kt < nk; ++kt) {
    if (kt + 1 < nk) STAGE(cur ^ 1, kt + 1);

    const _Float16* base = lds + cur * BUFH;
    half8 fa[4], fb[2];
    #pragma unroll
    for (int fm = 0; fm < 4; ++fm)
      fa[fm] = *(const half8*)(base + lg * 1024 + (wr * 64 + fm * 16 + lm) * 8);
    #pragma unroll
    for (int fn = 0; fn < 2; ++fn)
      fb[fn] = *(const half8*)(base + ATILE + lg * 512 + (wc * 32 + fn * 16 + lm) * 8);
    #pragma unroll
    for (int fm = 0; fm < 4; ++fm)
      #pragma unroll
      for (int fn = 0; fn < 2; ++fn)
        acc[fm][fn] = __builtin_amdgcn_mfma_f32_16x16x32_f16(fa[fm], fb[fn], acc[fm][fn], 0, 0, 0);

    // in-loop RNG: one 4-normal group per step (first 8 steps), fp16 regs.
    if (kt < 8) {
      f32x4 v = noise_group(kt, blockM, blockN, wr, wc, lg, lm, N, nk0, nk1);
      half4 hv;
      #pragma unroll
      for (int j = 0; j < 4; ++j) hv[j] = (_Float16)v[j];
      switch (kt) {
        case 0: nh0 = hv; break;  case 1: nh1 = hv; break;
        case 2: nh2 = hv; break;  case 3: nh3 = hv; break;
        case 4: nh4 = hv; break;  case 5: nh5 = hv; break;
        case 6: nh6 = hv; break;  default: nh7 = hv; break;
      }
    }

    __syncthreads();                   // drains staging; LDS free after loop
    cur ^= 1;
  }

  if (OUTMODE == 0) {
    // ---- G1 epilogue: swizzled-LDS transpose -> coalesced packed stores ----
#define EPI_STORE0(fm_, fn_, NZV)                                              \
    _Pragma("unroll")                                                          \
    for (int j = 0; j < 4; ++j) {                                              \
      float v = tanh_fast(fmaf(oscale, acc[fm_][fn_][j], bv))                  \
                + NOISE_LEVEL * (float)NZV[j];                                 \
      int R = wr * 64 + (fm_) * 16 + lg * 4 + j;                               \
      int C = wc * 32 + (fn_) * 16 + lm;                                       \
      lds[R * 64 + (C ^ ((R & 7) << 3))] = (_Float16)v;                        \
      cp += fabsf(v);                                                          \
    }
#define EPI_FN0(fn_, NZA, NZB, NZC, NZD) {                                     \
    const int gc = blockN + wc * 32 + (fn_)*16 + lm;                           \
    const float bv = bias[gc];                                                 \
    float cp = 0.0f;                                                           \
    EPI_STORE0(0, fn_, NZA) EPI_STORE0(1, fn_, NZB)                            \
    EPI_STORE0(2, fn_, NZC) EPI_STORE0(3, fn_, NZD)                            \
    cp += __shfl_xor(cp, 16);                                                  \
    cp += __shfl_xor(cp, 32);                                                  \
    if (lg == 0) atomicAdd(&colabs[gc], cp);                                   \
  }
    EPI_FN0(0, nh0, nh1, nh2, nh3)
    EPI_FN0(1, nh4, nh5, nh6, nh7)
    __syncthreads();
    _Float16* dstb = outn + ((size_t)bm * 64 + 2 * bn) * 4096;
    #pragma unroll
    for (int pp = 0; pp < 4; ++pp) {
      int gidx = pp * 256 + t;                 // 0..1023
      int row = gidx & 127;
      int kq = (gidx >> 7) & 3;
      int kh = gidx >> 9;
      int cbase = kh * 32 + kq * 8;
      half8 hv = *(const half8*)&lds[row * 64 + (cbase ^ ((row & 7) << 3))];
      *(half8*)&dstb[(size_t)kh * 4096 + kq * 1024 + row * 8] = hv;
    }
  } else {
    // ---- G2 epilogue: fused final (no global x2 write) ----
    const int gcA = blockN + wc * 32 + lm;          // fn = 0
    const int gcB = gcA + 16;                       // fn = 1
    const float bvA = bias[gcA], bvB = bias[gcB];
    const float w0A = Wout[gcA], w0B = Wout[gcB];
    const float w1A = Wout[2048 + gcA], w1B = Wout[2048 + gcB];
    float cpA = 0.0f, cpB = 0.0f;
    half4 vaA0, vaA1, vaA2, vaA3, vaB0, vaB1, vaB2, vaB3;
#define MKVA(fm_, dstA, dstB, NZA, NZB) {                                      \
    _Pragma("unroll")                                                          \
    for (int j = 0; j < 4; ++j) {                                              \
      float v = tanh_fast(fmaf(oscale, acc[fm_][0][j], bvA))                   \
                + NOISE_LEVEL * (float)NZA[j];                                 \
      dstA[j] = (_Float16)v; cpA += fabsf(v);                                  \
      float u = tanh_fast(fmaf(oscale, acc[fm_][1][j], bvB))                   \
                + NOISE_LEVEL * (float)NZB[j];                                 \
      dstB[j] = (_Float16)u; cpB += fabsf(u);                                  \
    } }
    MKVA(0, vaA0, vaB0, nh0, nh4) MKVA(1, vaA1, vaB1, nh1, nh5)
    MKVA(2, vaA2, vaB2, nh2, nh6) MKVA(3, vaA3, vaB3, nh3, nh7)
    cpA += __shfl_xor(cpA, 16);  cpA += __shfl_xor(cpA, 32);
    cpB += __shfl_xor(cpB, 16);  cpB += __shfl_xor(cpB, 32);
    if (lg == 0) { atomicAdd(&colabs[gcA], cpA); atomicAdd(&colabs[gcB], cpB); }
#define ROWDOT(fm_, vA, vB) {                                                  \
    _Pragma("unroll")                                                          \
    for (int j = 0; j < 4; ++j) {                                              \
      float s0 = fmaf((float)vA[j], w0A, (float)vB[j] * w0B);                  \
      float s1 = fmaf((float)vA[j], w1A, (float)vB[j] * w1B);                  \
      s0 += __shfl_xor(s0, 1); s0 += __shfl_xor(s0, 2);                        \
      s0 += __shfl_xor(s0, 4); s0 += __shfl_xor(s0, 8);                        \
      s1 += __shfl_xor(s1, 1); s1 += __shfl_xor(s1, 2);                        \
      s1 += __shfl_xor(s1, 4); s1 += __shfl_xor(s1, 8);                        \
      if (lm == 0) {                                                           \
        int r = blockM + wr * 64 + (fm_) * 16 + lg * 4 + j;                    \
        atomicAdd(&outf[r * 2 + 0], F_COH * s0);                               \
        atomicAdd(&outf[r * 2 + 1], F_COH * s1);                               \
      }                                                                        \
    } }
    ROWDOT(0, vaA0, vaB0) ROWDOT(1, vaA1, vaB1)
    ROWDOT(2, vaA2, vaB2) ROWDOT(3, vaA3, vaB3)
  }
#undef STAGE
}

// ---------------------------------------------------------------------------
// thermal = 0.7*prev + 0.3*(colabs*CROSSTALK); tn[i] = CROSSTALK * sum thermal[j]/(i-j)^2
// ---------------------------------------------------------------------------
__global__ __launch_bounds__(256)
void thermal_tn(const float* __restrict__ colabs, const float* __restrict__ prev_thermal,
                float* __restrict__ thermal_out, float* __restrict__ tn_out, int has_prev)
{
  __shared__ float th[2048];
  __shared__ float inv[2048];
  const int t = threadIdx.x;
  for (int j = t; j < 2048; j += 256) {
    float lt = colabs[j] * CROSSTALK;
    float pv = has_prev ? prev_thermal[j] : 0.0f;
    th[j] = 0.7f * pv + 0.3f * lt;
    float d = (float)j;
    inv[j] = (j == 0) ? 0.0f : 1.0f / (d * d);
  }
  __syncthreads();
  const int i = blockIdx.x * 256 + t;
  float s = 0.0f;
  #pragma unroll 4
  for (int j = 0; j < 2048; ++j) {
    int d = i - j; d = d < 0 ? -d : d;
    s += th[j] * inv[d];
  }
  tn_out[i] = s * CROSSTALK;
  thermal_out[i] = th[i];
}

// add_fold: out[i] += foldout[i & 1]   (after G2 atomics + bias_fold)
__global__ __launch_bounds__(256)
void add_fold(float* __restrict__ out, const float* __restrict__ foldout, int n)
{
  int i = blockIdx.x * 256 + threadIdx.x;
  if (i < n) out[i] += foldout[i & 1];
}

extern "C" void kernel_launch(void* const* d_in, const int* in_sizes, int n_in,
                              void* d_out, int out_size, void* d_ws, size_t ws_size,
                              hipStream_t stream)
{
  (void)in_sizes; (void)n_in; (void)ws_size;
  const float* x    = (const float*)d_in[0];
  const float* W1   = (const float*)d_in[1];
  const float* b1   = (const float*)d_in[2];
  const float* W2   = (const float*)d_in[3];
  const float* b2   = (const float*)d_in[4];
  const float* Wout = (const float*)d_in[5];
  const float* bout = (const float*)d_in[6];
  float* out = (float*)d_out;

  const int M = 8192, H = 2048, Din = 1024;
  const size_t MB = (size_t)1024 * 1024;

  char* ws = (char*)d_ws;
  // [0,32MB): a1 in G2-A packed layout (G1 writes via LDS-transpose epilogue)
  _Float16* a1pk = (_Float16*)ws;
  // [32,48MB): xpk (G1 A = tanh(x), packed)
  _Float16* xpk = (_Float16*)(ws + 32 * MB);
  // [48,52MB): W1 packed; [52,60MB): W2 packed
  _Float16* W1p = (_Float16*)(ws + 48 * MB);
  _Float16* W2p = (_Float16*)(ws + 52 * MB);
  // [64MB,...): small arrays
  float* small = (float*)(ws + 64 * MB);
  float* colabs1  = small + 0 * H;
  float* colabs2  = small + 1 * H;
  float* thermal1 = small + 2 * H;
  float* thermal2 = small + 3 * H;
  float* tn1      = small + 4 * H;
  float* tn2      = small + 5 * H;
  float* foldb    = small + 6 * H;
  float* foldout  = small + 7 * H;

  // fold_in keys: key(42) = (0,42); fold_in(key, d) = threefry(key, [0,d]).
  uint32_t kn0a, kn0b, kn1a, kn1b;
  threefry2x32(0u, 42u, 0u, 0u, kn0a, kn0b);   // noise, layer 0
  threefry2x32(0u, 42u, 0u, 2u, kn1a, kn1b);   // noise, layer 1

  hipMemsetAsync(colabs1, 0, 2 * H * sizeof(float), stream);
  hipMemsetAsync(out, 0, (size_t)out_size * sizeof(float), stream);

  // one fused pack launch (W1, W2, tanh(x)) - coalesced-read mapping
  pack_all<<<2048, 256, 0, stream>>>(W1, W2, x, W1p, W2p, xpk);

  const int nblk = (M / BM) * (H / BN);   // 64*32 = 2048
  gemm_f16<0><<<nblk, 256, 0, stream>>>(xpk, W1p, b1, a1pk, colabs1,
                                        nullptr, nullptr,
                                        M, H, Din, 1.0f, kn0a, kn0b);
  thermal_tn<<<H / 256, 256, 0, stream>>>(colabs1, nullptr, thermal1, tn1, 0);
  // foldb = b2 + F*(tn1 @ W2^T); G2 computes tanh(F*(a1@W2^T) + foldb) + noise
  bias_fold<<<H / 4, 256, 0, stream>>>(tn1, W2, b2, foldb, H, H, F_COH);
  gemm_f16<1><<<nblk, 256, 0, stream>>>(a1pk, W2p, foldb, nullptr, colabs2,
                                        Wout, out,
                                        M, H, H, F_COH, kn1a, kn1b);
  thermal_tn<<<H / 256, 256, 0, stream>>>(colabs2, thermal1, thermal2, tn2, 1);
  // foldout = bout + F*(tn2 @ Wout^T)
  bias_fold<<<1, 256, 0, stream>>>(tn2, Wout, bout, foldout, H, 2, F_COH);
  add_fold<<<(2 * M + 255) / 256, 256, 0, stream>>>(out, foldout, 2 * M);
}

// Round 15
// 350.677 us; speedup vs baseline: 1.0913x; 1.0913x over previous
//
#include <hip/hip_runtime.h>
#include <stdint.h>
#include <math.h>

#define NOISE_LEVEL 0.02f
#define CROSSTALK   0.05f
#define COHERENCE   0.03f
// coherence factor with E[n^2]=1: 1 + 0.03*(exp(-0.03^2/2)-1) = 1 - 1.3497e-5
#define F_COH 0.99998650f

typedef _Float16 half8 __attribute__((ext_vector_type(8)));
typedef _Float16 half4 __attribute__((ext_vector_type(4)));
typedef __attribute__((ext_vector_type(4))) float f32x4;

#define TF_ROUND(x0,x1,R) { x0 += x1; x1 = ((x1 << (R)) | (x1 >> (32-(R)))); x1 ^= x0; }

__host__ __device__ inline void threefry2x32(uint32_t k0, uint32_t k1,
                                             uint32_t x0, uint32_t x1,
                                             uint32_t& o0, uint32_t& o1)
{
  uint32_t ks2 = k0 ^ k1 ^ 0x1BD11BDAu;
  x0 += k0; x1 += k1;
  TF_ROUND(x0,x1,13) TF_ROUND(x0,x1,15) TF_ROUND(x0,x1,26) TF_ROUND(x0,x1,6)
  x0 += k1; x1 += ks2 + 1u;
  TF_ROUND(x0,x1,17) TF_ROUND(x0,x1,29) TF_ROUND(x0,x1,16) TF_ROUND(x0,x1,24)
  x0 += ks2; x1 += k0 + 2u;
  TF_ROUND(x0,x1,13) TF_ROUND(x0,x1,15) TF_ROUND(x0,x1,26) TF_ROUND(x0,x1,6)
  x0 += k0; x1 += k1 + 3u;
  TF_ROUND(x0,x1,17) TF_ROUND(x0,x1,29) TF_ROUND(x0,x1,16) TF_ROUND(x0,x1,24)
  x0 += k1; x1 += ks2 + 4u;
  TF_ROUND(x0,x1,13) TF_ROUND(x0,x1,15) TF_ROUND(x0,x1,26) TF_ROUND(x0,x1,6)
  o0 = x0 + ks2; o1 = x1 + k0 + 5u;
}

// threefry_partitionable bits for 32-bit draws: XOR of the two output words.
__device__ inline uint32_t jax_bits(uint32_t k0, uint32_t k1, uint32_t idx)
{
  uint32_t o0, o1; threefry2x32(k0, k1, 0u, idx, o0, o1); return o0 ^ o1;
}

// JAX random.normal(float32): u ~ uniform[-0.99999994, 1); n = sqrt(2)*erfinv(u)
__device__ inline float jax_normal(uint32_t k0, uint32_t k1, uint32_t idx)
{
  uint32_t bits = jax_bits(k0, k1, idx);
  float f = __uint_as_float((bits >> 9) | 0x3f800000u) - 1.0f;   // [0,1)
  float u = fmaf(f, 2.0f, -0.99999994f);
  u = fmaxf(-0.99999994f, u);
  float w = -__logf(fmaf(-u, u, 1.0f));
  float wl = w - 2.5f;
  float p = 2.81022636e-08f;
  p = fmaf(p, wl, 3.43273939e-07f);
  p = fmaf(p, wl, -3.5233877e-06f);
  p = fmaf(p, wl, -4.39150654e-06f);
  p = fmaf(p, wl, 0.00021858087f);
  p = fmaf(p, wl, -0.00125372503f);
  p = fmaf(p, wl, -0.00417768164f);
  p = fmaf(p, wl, 0.246640727f);
  p = fmaf(p, wl, 1.50140941f);
  if (__any(w >= 5.0f)) {
    float ws = sqrtf(w) - 3.0f;
    float q = -0.000200214257f;
    q = fmaf(q, ws, 0.000100950558f);
    q = fmaf(q, ws, 0.00134934322f);
    q = fmaf(q, ws, -0.00367342844f);
    q = fmaf(q, ws, 0.00573950773f);
    q = fmaf(q, ws, -0.0076224613f);
    q = fmaf(q, ws, 0.00943887047f);
    q = fmaf(q, ws, 1.00167406f);
    q = fmaf(q, ws, 2.83297682f);
    p = (w >= 5.0f) ? q : p;
  }
  return 1.41421354f * (p * u);
}

// exact-algebra tanh via fast exp; abs err <= ~1.2e-7, inf-safe.
__device__ inline float tanh_fast(float x)
{
  float ax = fabsf(x);
  float e = __expf(2.0f * ax);
  float r = 1.0f - 2.0f / (e + 1.0f);
  return copysignf(r, x);
}

// ---------------------------------------------------------------------------
// Packed fp16 operand layout (BK=32, row-block RB = 1<<rbbits):
//   tile (rb,kt) occupies RB*32 halves at (rb*ktiles + kt)*RB*32,
//   internally [kq(4)][row(RB)][8].
// A planes: RB=128 (rbbits=7); B/W planes: RB=64 (rbbits=6) = BN.
// Thread->slot mapping (kq = s&3, row = s>>2): 4 consecutive threads read one
// ROW's 32 consecutive floats (128B coalesced); writes form 256B runs.
// ---------------------------------------------------------------------------
__global__ __launch_bounds__(256)
void pack_all(const float* __restrict__ W1, const float* __restrict__ W2,
              const float* __restrict__ x,
              _Float16* __restrict__ W1p, _Float16* __restrict__ W2p,
              _Float16* __restrict__ xpk)
{
  const int n0 = (2048 * 1024) / 8;     // W1 slots
  const int n1 = (2048 * 2048) / 8;     // W2 slots
  const int n2 = (8192 * 1024) / 8;     // x  slots
  const int total = n0 + n1 + n2;
  int g = blockIdx.x * 256 + threadIdx.x;
  const int stride = gridDim.x * 256;
  for (; g < total; g += stride) {
    const float* in; _Float16* out;
    int gg, K, kshift, rbbits, do_tanh;
    if (g < n0)           { in = W1; out = W1p; gg = g;           K = 1024; kshift = 5; rbbits = 6; do_tanh = 0; }
    else if (g < n0 + n1) { in = W2; out = W2p; gg = g - n0;      K = 2048; kshift = 6; rbbits = 6; do_tanh = 0; }
    else                  { in = x;  out = xpk; gg = g - n0 - n1; K = 1024; kshift = 5; rbbits = 7; do_tanh = 1; }
    const int ktm = (K >> 5) - 1;
    const int slotbits = rbbits + 2;
    int tile = gg >> slotbits;
    int s = gg & ((1 << slotbits) - 1);
    int kq = s & 3, row = s >> 2;                 // coalesced-read mapping
    int rb = tile >> kshift, kt = tile & ktm;
    int r = (rb << rbbits) + row;
    int k = kt * 32 + kq * 8;
    const float* src = in + (size_t)r * K + k;
    float4 v0 = *(const float4*)src;
    float4 v1 = *(const float4*)(src + 4);
    float xs[8] = {v0.x, v0.y, v0.z, v0.w, v1.x, v1.y, v1.z, v1.w};
    half8 h;
    #pragma unroll
    for (int e = 0; e < 8; ++e) {
      float xv = do_tanh ? tanh_fast(xs[e]) : xs[e];
      h[e] = (_Float16)xv;
    }
    size_t oslot = ((size_t)tile << slotbits) + (kq << rbbits) + row;
    *(half8*)&out[oslot * 8] = h;
  }
}

// fragment-native fp16 output layout for 128x64 C blocks (N=2048, nbn=32):
//   idx = ((blk*4 + w)*32 + fn*16 + fm*4 + j)*64 + lane
__device__ __forceinline__ size_t cnat_idx(int r, int c)
{
  int bm = r >> 7, bn = c >> 6, rr = r & 127, cc = c & 63;
  int w = ((rr >> 6) << 1) | (cc >> 5);
  int fm = (rr >> 4) & 3, lg = (rr >> 2) & 3, j = rr & 3;
  int fn = (cc >> 4) & 1, lm = cc & 15;
  return (((size_t)(bm * 32 + bn) * 4 + w) * 32 + fn * 16 + fm * 4 + j) * 64
         + lg * 16 + lm;
}

// bias_fold: fold[j] = b[j] + scale * sum_h tn[h] * W[j,h]  (fp32; one wave/j)
__global__ __launch_bounds__(256)
void bias_fold(const float* __restrict__ tn, const float* __restrict__ W,
               const float* __restrict__ b, float* __restrict__ fold,
               int K, int nrows, float scale)
{
  const int wid = threadIdx.x >> 6;
  const int lane = threadIdx.x & 63;
  const int j = blockIdx.x * 4 + wid;
  if (j >= nrows) return;
  const float* row = W + (size_t)j * K;
  float s = 0.0f;
  for (int h = lane; h < K; h += 64) s = fmaf(tn[h], row[h], s);
  #pragma unroll
  for (int off = 32; off > 0; off >>= 1) s += __shfl_down(s, off);
  if (lane == 0) fold[j] = fmaf(scale, s, b[j]);
}

// ---------------------------------------------------------------------------
// fp16 MFMA GEMM, BM=128 x BN=64, BK=32, 4 waves, R11/R13 double-buffered loop
// (R12 counted-vmcnt and R14 fused-final both regressed; reverted).
//   v = tanh(oscale*acc + bias) + 0.02*normal(key, r*N+c); colabs += sum|v|.
// OUTMODE 0 (G1): epilogue transposes C through XOR-swizzled LDS then stores
//   the block's 64KB in EXACT a1pk packed order (coalesced, no L2 RMW).
// OUTMODE 1 (G2): fragment-native 128x64 layout (final_out decodes).
// Block order: XCD region 16bm x 16bn in 4bm x 8bn L2 sub-chunks.
// ---------------------------------------------------------------------------
#define BM 128
#define BN 64
#define ATILE 4096            // halves per A tile (128*32)
#define BTILE 2048            // halves per B tile (64*32)
#define BUFH  (ATILE + BTILE)

__device__ __forceinline__ f32x4 noise_group(int g, int blockM, int blockN,
                                             int wr, int wc, int lg, int lm,
                                             int N, uint32_t k0, uint32_t k1)
{
  int fn = g >> 2, fm = g & 3;
  int gr0 = blockM + wr * 64 + fm * 16 + lg * 4;
  int gc  = blockN + wc * 32 + fn * 16 + lm;
  f32x4 r;
  #pragma unroll
  for (int j = 0; j < 4; ++j)
    r[j] = jax_normal(k0, k1, (uint32_t)((gr0 + j) * N + gc));
  return r;
}

template<int OUTMODE>
__global__ __launch_bounds__(256, 5)
void gemm_f16(const _Float16* __restrict__ Ap, const _Float16* __restrict__ Bp,
              const float* __restrict__ bias, _Float16* __restrict__ outn,
              float* __restrict__ colabs, int M, int N, int K, float oscale,
              uint32_t nk0, uint32_t nk1)
{
  __shared__ __align__(16) _Float16 lds[2 * BUFH];   // 24 KiB

  const int t = threadIdx.x;
  // XCD-region + L2-sub-chunk block order (grid = 64bm x 32bn, 8 XCDs)
  const int bid = blockIdx.x;
  const int xcd = bid & 7, p = bid >> 3;       // p in [0,256) per XCD
  const int s = p >> 5, q = p & 31;            // 8 sub-chunks of 32 blocks
  const int bm = ((xcd >> 1) << 4) + ((s >> 1) << 2) + (q >> 3);
  const int bn = ((xcd & 1) << 4) + ((s & 1) << 3) + (q & 7);
  const int blockM = bm * BM, blockN = bn * BN;

  const int lane = t & 63;
  const int w = t >> 6;
  const int wr = w >> 1, wc = w & 1;
  const int lm = lane & 15, lg = lane >> 4;

  const int ktiles = K >> 5;

  // staging: 12 x 1KB global_load_lds per k-tile; wave w issues loads 3w..3w+2
  const _Float16* gsrc[3];
  int gstride[3];
  _Float16* ldst[3];
  #pragma unroll
  for (int i = 0; i < 3; ++i) {
    int l = w * 3 + i;
    if (l < 8) {
      gsrc[i] = Ap + ((size_t)bm * ktiles) * ATILE + l * 512 + lane * 8;
      gstride[i] = ATILE;
      ldst[i] = lds + l * 512;
    } else {
      gsrc[i] = Bp + ((size_t)bn * ktiles) * BTILE + (l - 8) * 512 + lane * 8;
      gstride[i] = BTILE;
      ldst[i] = lds + ATILE + (l - 8) * 512;
    }
  }

#define STAGE(buf, kt_) {                                                      \
    _Pragma("unroll")                                                          \
    for (int i = 0; i < 3; ++i)                                                \
      __builtin_amdgcn_global_load_lds(                                        \
          (const void*)(gsrc[i] + (size_t)(kt_) * gstride[i]),                 \
          (void*)(ldst[i] + (buf) * BUFH), 16, 0, 0);                          \
  }

  f32x4 acc[4][2];
  #pragma unroll
  for (int i = 0; i < 4; ++i)
    #pragma unroll
    for (int j = 0; j < 2; ++j) acc[i][j] = 0.0f;

  half4 nh0 = 0, nh1 = 0, nh2 = 0, nh3 = 0, nh4 = 0, nh5 = 0, nh6 = 0, nh7 = 0;

  const int nk = ktiles;               // 32 (G1) or 64 (G2)
  STAGE(0, 0);
  __syncthreads();
  int cur = 0;

  for (int kt = 0; kt < nk; ++kt) {
    if (kt + 1 < nk) STAGE(cur ^ 1, kt + 1);

    const _Float16* base = lds + cur * BUFH;
    half8 fa[4], fb[2];
    #pragma unroll
    for (int fm = 0; fm < 4; ++fm)
      fa[fm] = *(const half8*)(base + lg * 1024 + (wr * 64 + fm * 16 + lm) * 8);
    #pragma unroll
    for (int fn = 0; fn < 2; ++fn)
      fb[fn] = *(const half8*)(base + ATILE + lg * 512 + (wc * 32 + fn * 16 + lm) * 8);
    #pragma unroll
    for (int fm = 0; fm < 4; ++fm)
      #pragma unroll
      for (int fn = 0; fn < 2; ++fn)
        acc[fm][fn] = __builtin_amdgcn_mfma_f32_16x16x32_f16(fa[fm], fb[fn], acc[fm][fn], 0, 0, 0);

    // in-loop RNG: one 4-normal group per step (first 8 steps), fp16 regs.
    if (kt < 8) {
      f32x4 v = noise_group(kt, blockM, blockN, wr, wc, lg, lm, N, nk0, nk1);
      half4 hv;
      #pragma unroll
      for (int j = 0; j < 4; ++j) hv[j] = (_Float16)v[j];
      switch (kt) {
        case 0: nh0 = hv; break;  case 1: nh1 = hv; break;
        case 2: nh2 = hv; break;  case 3: nh3 = hv; break;
        case 4: nh4 = hv; break;  case 5: nh5 = hv; break;
        case 6: nh6 = hv; break;  default: nh7 = hv; break;
      }
    }

    __syncthreads();                   // drains staging; LDS free after loop
    cur ^= 1;
  }

  // ---- epilogue ----
  const size_t obase1 = (((size_t)(bm * 32 + bn) * 4 + w) * 32) * 64 + lane;

#define EPI_STORE(fm_, fn_, NZV)                                               \
    _Pragma("unroll")                                                          \
    for (int j = 0; j < 4; ++j) {                                              \
      float v = tanh_fast(fmaf(oscale, acc[fm_][fn_][j], bv))                  \
                + NOISE_LEVEL * (float)NZV[j];                                 \
      if (OUTMODE == 0) {                                                      \
        int R = wr * 64 + (fm_) * 16 + lg * 4 + j;                             \
        int C = wc * 32 + (fn_) * 16 + lm;                                     \
        lds[R * 64 + (C ^ ((R & 7) << 3))] = (_Float16)v;                      \
      } else {                                                                 \
        outn[obase1 + (size_t)((fn_)*16 + (fm_)*4 + j) * 64] = (_Float16)v;    \
      }                                                                        \
      cp += fabsf(v);                                                          \
    }

#define EPI_FN(fn_, NZA, NZB, NZC, NZD) {                                      \
    const int gc = blockN + wc * 32 + (fn_)*16 + lm;                           \
    const float bv = bias[gc];                                                 \
    float cp = 0.0f;                                                           \
    EPI_STORE(0, fn_, NZA) EPI_STORE(1, fn_, NZB)                              \
    EPI_STORE(2, fn_, NZC) EPI_STORE(3, fn_, NZD)                              \
    cp += __shfl_xor(cp, 16);                                                  \
    cp += __shfl_xor(cp, 32);                                                  \
    if (lg == 0) atomicAdd(&colabs[gc], cp);                                   \
  }

  EPI_FN(0, nh0, nh1, nh2, nh3)
  EPI_FN(1, nh4, nh5, nh6, nh7)

  if (OUTMODE == 0) {
    // phase 2: coalesced packed-order stores. Block covers a1pk tiles
    // (rb=bm, kt = 2*bn + kh), kh in {0,1}; granule (kh,kq,row) -> 16B.
    __syncthreads();
    _Float16* dstb = outn + ((size_t)bm * 64 + 2 * bn) * 4096;
    #pragma unroll
    for (int pp = 0; pp < 4; ++pp) {
      int gidx = pp * 256 + t;                 // 0..1023
      int row = gidx & 127;
      int kq = (gidx >> 7) & 3;
      int kh = gidx >> 9;
      int cbase = kh * 32 + kq * 8;
      half8 hv = *(const half8*)&lds[row * 64 + (cbase ^ ((row & 7) << 3))];
      *(half8*)&dstb[(size_t)kh * 4096 + kq * 1024 + row * 8] = hv;
    }
  }
#undef EPI_FN
#undef EPI_STORE
#undef STAGE
}

// ---------------------------------------------------------------------------
// thermal = 0.7*prev + 0.3*(colabs*CROSSTALK); tn[i] = CROSSTALK * sum thermal[j]/(i-j)^2
// ---------------------------------------------------------------------------
__global__ __launch_bounds__(256)
void thermal_tn(const float* __restrict__ colabs, const float* __restrict__ prev_thermal,
                float* __restrict__ thermal_out, float* __restrict__ tn_out, int has_prev)
{
  __shared__ float th[2048];
  __shared__ float inv[2048];
  const int t = threadIdx.x;
  for (int j = t; j < 2048; j += 256) {
    float lt = colabs[j] * CROSSTALK;
    float pv = has_prev ? prev_thermal[j] : 0.0f;
    th[j] = 0.7f * pv + 0.3f * lt;
    float d = (float)j;
    inv[j] = (j == 0) ? 0.0f : 1.0f / (d * d);
  }
  __syncthreads();
  const int i = blockIdx.x * 256 + t;
  float s = 0.0f;
  #pragma unroll 4
  for (int j = 0; j < 2048; ++j) {
    int d = i - j; d = d < 0 ? -d : d;
    s += th[j] * inv[d];
  }
  tn_out[i] = s * CROSSTALK;
  thermal_out[i] = th[i];
}

// ---------------------------------------------------------------------------
// Final: out[b,:] = F_COH * (x2[b,:] @ Wout^T) + foldout  (coherence + thermal
// folded into scale/bias; no RNG). a2 is fragment-native fp16 (128x64 blocks).
// ---------------------------------------------------------------------------
__global__ __launch_bounds__(256)
void final_out(const _Float16* __restrict__ a2n, const float* __restrict__ Wout,
               const float* __restrict__ foldout, float* __restrict__ out)
{
  const int wave = threadIdx.x >> 6;
  const int lane = threadIdx.x & 63;
  const int b = blockIdx.x * 4 + wave;
  float acc0 = 0.0f, acc1 = 0.0f;
  #pragma unroll
  for (int i = 0; i < 8; ++i) {
    int h = lane * 4 + i * 256;
    half4 v4 = *(const half4*)&a2n[cnat_idx(b, h)];
    float4 w0 = *(const float4*)&Wout[h];
    float4 w1 = *(const float4*)&Wout[2048 + h];
    float xs[4]  = {(float)v4[0], (float)v4[1], (float)v4[2], (float)v4[3]};
    float w0s[4] = {w0.x, w0.y, w0.z, w0.w};
    float w1s[4] = {w1.x, w1.y, w1.z, w1.w};
    #pragma unroll
    for (int e = 0; e < 4; ++e) {
      acc0 = fmaf(xs[e], w0s[e], acc0);
      acc1 = fmaf(xs[e], w1s[e], acc1);
    }
  }
  #pragma unroll
  for (int off = 32; off > 0; off >>= 1) {
    acc0 += __shfl_down(acc0, off);
    acc1 += __shfl_down(acc1, off);
  }
  if (lane == 0) {
    out[(size_t)b * 2 + 0] = fmaf(F_COH, acc0, foldout[0]);
    out[(size_t)b * 2 + 1] = fmaf(F_COH, acc1, foldout[1]);
  }
}

extern "C" void kernel_launch(void* const* d_in, const int* in_sizes, int n_in,
                              void* d_out, int out_size, void* d_ws, size_t ws_size,
                              hipStream_t stream)
{
  (void)in_sizes; (void)n_in; (void)out_size; (void)ws_size;
  const float* x    = (const float*)d_in[0];
  const float* W1   = (const float*)d_in[1];
  const float* b1   = (const float*)d_in[2];
  const float* W2   = (const float*)d_in[3];
  const float* b2   = (const float*)d_in[4];
  const float* Wout = (const float*)d_in[5];
  const float* bout = (const float*)d_in[6];
  float* out = (float*)d_out;

  const int M = 8192, H = 2048, Din = 1024;
  const size_t MB = (size_t)1024 * 1024;

  char* ws = (char*)d_ws;
  // [0,32MB): a2 fragment-native fp16 (G2 out)
  _Float16* a2n = (_Float16*)ws;
  // [32,64MB): a1 in G2-A packed layout (G1 writes via LDS-transpose epilogue)
  _Float16* a1pk = (_Float16*)(ws + 32 * MB);
  // [64,80MB): xpk (G1 A = tanh(x), packed)
  _Float16* xpk = (_Float16*)(ws + 64 * MB);
  // [80,84MB): W1 packed; [84,92MB): W2 packed
  _Float16* W1p = (_Float16*)(ws + 80 * MB);
  _Float16* W2p = (_Float16*)(ws + 84 * MB);
  // [96MB,...): small arrays
  float* small = (float*)(ws + 96 * MB);
  float* colabs1  = small + 0 * H;
  float* colabs2  = small + 1 * H;
  float* thermal1 = small + 2 * H;
  float* thermal2 = small + 3 * H;
  float* tn1      = small + 4 * H;
  float* tn2      = small + 5 * H;
  float* foldb    = small + 6 * H;
  float* foldout  = small + 7 * H;

  // fold_in keys: key(42) = (0,42); fold_in(key, d) = threefry(key, [0,d]).
  uint32_t kn0a, kn0b, kn1a, kn1b;
  threefry2x32(0u, 42u, 0u, 0u, kn0a, kn0b);   // noise, layer 0
  threefry2x32(0u, 42u, 0u, 2u, kn1a, kn1b);   // noise, layer 1

  hipMemsetAsync(colabs1, 0, 2 * H * sizeof(float), stream);

  // one fused pack launch (W1, W2, tanh(x)) - coalesced-read mapping
  pack_all<<<2048, 256, 0, stream>>>(W1, W2, x, W1p, W2p, xpk);

  const int nblk = (M / BM) * (H / BN);   // 64*32 = 2048
  gemm_f16<0><<<nblk, 256, 0, stream>>>(xpk, W1p, b1, a1pk, colabs1,
                                        M, H, Din, 1.0f, kn0a, kn0b);
  thermal_tn<<<H / 256, 256, 0, stream>>>(colabs1, nullptr, thermal1, tn1, 0);
  // foldb = b2 + F*(tn1 @ W2^T); G2 computes tanh(F*(a1@W2^T) + foldb) + noise
  bias_fold<<<H / 4, 256, 0, stream>>>(tn1, W2, b2, foldb, H, H, F_COH);
  gemm_f16<1><<<nblk, 256, 0, stream>>>(a1pk, W2p, foldb, a2n, colabs2,
                                        M, H, H, F_COH, kn1a, kn1b);
  thermal_tn<<<H / 256, 256, 0, stream>>>(colabs2, thermal1, thermal2, tn2, 1);
  // foldout = bout + F*(tn2 @ Wout^T)
  bias_fold<<<1, 256, 0, stream>>>(tn2, Wout, bout, foldout, H, 2, F_COH);
  final_out<<<M / 4, 256, 0, stream>>>(a2n, Wout, foldout, out);
}

// Round 16
// 349.565 us; speedup vs baseline: 1.0947x; 1.0032x over previous
//
#include <hip/hip_runtime.h>
#include <stdint.h>
#include <math.h>

#define NOISE_LEVEL 0.02f
#define CROSSTALK   0.05f
#define COHERENCE   0.03f
// coherence factor with E[n^2]=1: 1 + 0.03*(exp(-0.03^2/2)-1) = 1 - 1.3497e-5
#define F_COH 0.99998650f

typedef _Float16 half8 __attribute__((ext_vector_type(8)));
typedef _Float16 half4 __attribute__((ext_vector_type(4)));
typedef __attribute__((ext_vector_type(4))) float f32x4;

#define TF_ROUND(x0,x1,R) { x0 += x1; x1 = ((x1 << (R)) | (x1 >> (32-(R)))); x1 ^= x0; }

__host__ __device__ inline void threefry2x32(uint32_t k0, uint32_t k1,
                                             uint32_t x0, uint32_t x1,
                                             uint32_t& o0, uint32_t& o1)
{
  uint32_t ks2 = k0 ^ k1 ^ 0x1BD11BDAu;
  x0 += k0; x1 += k1;
  TF_ROUND(x0,x1,13) TF_ROUND(x0,x1,15) TF_ROUND(x0,x1,26) TF_ROUND(x0,x1,6)
  x0 += k1; x1 += ks2 + 1u;
  TF_ROUND(x0,x1,17) TF_ROUND(x0,x1,29) TF_ROUND(x0,x1,16) TF_ROUND(x0,x1,24)
  x0 += ks2; x1 += k0 + 2u;
  TF_ROUND(x0,x1,13) TF_ROUND(x0,x1,15) TF_ROUND(x0,x1,26) TF_ROUND(x0,x1,6)
  x0 += k0; x1 += k1 + 3u;
  TF_ROUND(x0,x1,17) TF_ROUND(x0,x1,29) TF_ROUND(x0,x1,16) TF_ROUND(x0,x1,24)
  x0 += k1; x1 += ks2 + 4u;
  TF_ROUND(x0,x1,13) TF_ROUND(x0,x1,15) TF_ROUND(x0,x1,26) TF_ROUND(x0,x1,6)
  o0 = x0 + ks2; o1 = x1 + k0 + 5u;
}

// threefry_partitionable bits for 32-bit draws: XOR of the two output words.
__device__ inline uint32_t jax_bits(uint32_t k0, uint32_t k1, uint32_t idx)
{
  uint32_t o0, o1; threefry2x32(k0, k1, 0u, idx, o0, o1); return o0 ^ o1;
}

// JAX random.normal(float32): u ~ uniform[-0.99999994, 1); n = sqrt(2)*erfinv(u)
__device__ inline float jax_normal(uint32_t k0, uint32_t k1, uint32_t idx)
{
  uint32_t bits = jax_bits(k0, k1, idx);
  float f = __uint_as_float((bits >> 9) | 0x3f800000u) - 1.0f;   // [0,1)
  float u = fmaf(f, 2.0f, -0.99999994f);
  u = fmaxf(-0.99999994f, u);
  float w = -__logf(fmaf(-u, u, 1.0f));
  float wl = w - 2.5f;
  float p = 2.81022636e-08f;
  p = fmaf(p, wl, 3.43273939e-07f);
  p = fmaf(p, wl, -3.5233877e-06f);
  p = fmaf(p, wl, -4.39150654e-06f);
  p = fmaf(p, wl, 0.00021858087f);
  p = fmaf(p, wl, -0.00125372503f);
  p = fmaf(p, wl, -0.00417768164f);
  p = fmaf(p, wl, 0.246640727f);
  p = fmaf(p, wl, 1.50140941f);
  if (__any(w >= 5.0f)) {
    float ws = sqrtf(w) - 3.0f;
    float q = -0.000200214257f;
    q = fmaf(q, ws, 0.000100950558f);
    q = fmaf(q, ws, 0.00134934322f);
    q = fmaf(q, ws, -0.00367342844f);
    q = fmaf(q, ws, 0.00573950773f);
    q = fmaf(q, ws, -0.0076224613f);
    q = fmaf(q, ws, 0.00943887047f);
    q = fmaf(q, ws, 1.00167406f);
    q = fmaf(q, ws, 2.83297682f);
    p = (w >= 5.0f) ? q : p;
  }
  return 1.41421354f * (p * u);
}

// exact-algebra tanh via fast exp; abs err <= ~1.2e-7, inf-safe.
__device__ inline float tanh_fast(float x)
{
  float ax = fabsf(x);
  float e = __expf(2.0f * ax);
  float r = 1.0f - 2.0f / (e + 1.0f);
  return copysignf(r, x);
}

// ---------------------------------------------------------------------------
// Packed fp16 operand layout (BK=32, row-block RB = 1<<rbbits):
//   tile (rb,kt) occupies RB*32 halves at (rb*ktiles + kt)*RB*32,
//   internally [kq(4)][row(RB)][8].
// A planes: RB=128 (rbbits=7); B/W planes: RB=64 (rbbits=6) = BN.
// Thread->slot mapping (kq = s&3, row = s>>2): 4 consecutive threads read one
// ROW's 32 consecutive floats (128B coalesced); writes form 256B runs.
// ---------------------------------------------------------------------------
__global__ __launch_bounds__(256)
void pack_all(const float* __restrict__ W1, const float* __restrict__ W2,
              const float* __restrict__ x,
              _Float16* __restrict__ W1p, _Float16* __restrict__ W2p,
              _Float16* __restrict__ xpk)
{
  const int n0 = (2048 * 1024) / 8;     // W1 slots
  const int n1 = (2048 * 2048) / 8;     // W2 slots
  const int n2 = (8192 * 1024) / 8;     // x  slots
  const int total = n0 + n1 + n2;
  int g = blockIdx.x * 256 + threadIdx.x;
  const int stride = gridDim.x * 256;
  for (; g < total; g += stride) {
    const float* in; _Float16* out;
    int gg, K, kshift, rbbits, do_tanh;
    if (g < n0)           { in = W1; out = W1p; gg = g;           K = 1024; kshift = 5; rbbits = 6; do_tanh = 0; }
    else if (g < n0 + n1) { in = W2; out = W2p; gg = g - n0;      K = 2048; kshift = 6; rbbits = 6; do_tanh = 0; }
    else                  { in = x;  out = xpk; gg = g - n0 - n1; K = 1024; kshift = 5; rbbits = 7; do_tanh = 1; }
    const int ktm = (K >> 5) - 1;
    const int slotbits = rbbits + 2;
    int tile = gg >> slotbits;
    int s = gg & ((1 << slotbits) - 1);
    int kq = s & 3, row = s >> 2;                 // coalesced-read mapping
    int rb = tile >> kshift, kt = tile & ktm;
    int r = (rb << rbbits) + row;
    int k = kt * 32 + kq * 8;
    const float* src = in + (size_t)r * K + k;
    float4 v0 = *(const float4*)src;
    float4 v1 = *(const float4*)(src + 4);
    float xs[8] = {v0.x, v0.y, v0.z, v0.w, v1.x, v1.y, v1.z, v1.w};
    half8 h;
    #pragma unroll
    for (int e = 0; e < 8; ++e) {
      float xv = do_tanh ? tanh_fast(xs[e]) : xs[e];
      h[e] = (_Float16)xv;
    }
    size_t oslot = ((size_t)tile << slotbits) + (kq << rbbits) + row;
    *(half8*)&out[oslot * 8] = h;
  }
}

// fragment-native fp16 output layout for 128x64 C blocks (N=2048, nbn=32):
//   idx = ((blk*4 + w)*32 + fn*16 + fm*4 + j)*64 + lane
__device__ __forceinline__ size_t cnat_idx(int r, int c)
{
  int bm = r >> 7, bn = c >> 6, rr = r & 127, cc = c & 63;
  int w = ((rr >> 6) << 1) | (cc >> 5);
  int fm = (rr >> 4) & 3, lg = (rr >> 2) & 3, j = rr & 3;
  int fn = (cc >> 4) & 1, lm = cc & 15;
  return (((size_t)(bm * 32 + bn) * 4 + w) * 32 + fn * 16 + fm * 4 + j) * 64
         + lg * 16 + lm;
}

// bias_fold: fold[j] = b[j] + scale * sum_h tn[h] * W[j,h]  (fp32; one wave/j)
__global__ __launch_bounds__(256)
void bias_fold(const float* __restrict__ tn, const float* __restrict__ W,
               const float* __restrict__ b, float* __restrict__ fold,
               int K, int nrows, float scale)
{
  const int wid = threadIdx.x >> 6;
  const int lane = threadIdx.x & 63;
  const int j = blockIdx.x * 4 + wid;
  if (j >= nrows) return;
  const float* row = W + (size_t)j * K;
  float s = 0.0f;
  for (int h = lane; h < K; h += 64) s = fmaf(tn[h], row[h], s);
  #pragma unroll
  for (int off = 32; off > 0; off >>= 1) s += __shfl_down(s, off);
  if (lane == 0) fold[j] = fmaf(scale, s, b[j]);
}

// ---------------------------------------------------------------------------
// fp16 MFMA GEMM, BM=128 x BN=64, BK=32, 4 waves, double-buffered loop.
//   v = tanh(oscale*acc + bias) + 0.02*normal(key, r*N+c); colabs += sum|v|.
// R16 change (numerics-identical): the 8 noise groups are spread EVENLY over
// the K-loop ((kt & mask)==1, group = kt>>RSHIFT) instead of bursting into
// the first 8 iterations; per-normal index multiplies hoisted to one base;
// staging addresses use pointer increments (no per-iter mul).
// OUTMODE 0 (G1): LDS-transpose epilogue -> coalesced a1pk packed stores.
// OUTMODE 1 (G2): fragment-native 128x64 layout (final_out decodes).
// Block order: XCD region 16bm x 16bn in 4bm x 8bn L2 sub-chunks.
// ---------------------------------------------------------------------------
#define BM 128
#define BN 64
#define ATILE 4096            // halves per A tile (128*32)
#define BTILE 2048            // halves per B tile (64*32)
#define BUFH  (ATILE + BTILE)

template<int OUTMODE, int RSHIFT>
__global__ __launch_bounds__(256, 5)
void gemm_f16(const _Float16* __restrict__ Ap, const _Float16* __restrict__ Bp,
              const float* __restrict__ bias, _Float16* __restrict__ outn,
              float* __restrict__ colabs, int M, int N, int K, float oscale,
              uint32_t nk0, uint32_t nk1)
{
  __shared__ __align__(16) _Float16 lds[2 * BUFH];   // 24 KiB

  const int t = threadIdx.x;
  // XCD-region + L2-sub-chunk block order (grid = 64bm x 32bn, 8 XCDs)
  const int bid = blockIdx.x;
  const int xcd = bid & 7, p = bid >> 3;       // p in [0,256) per XCD
  const int s = p >> 5, q = p & 31;            // 8 sub-chunks of 32 blocks
  const int bm = ((xcd >> 1) << 4) + ((s >> 1) << 2) + (q >> 3);
  const int bn = ((xcd & 1) << 4) + ((s & 1) << 3) + (q & 7);
  const int blockM = bm * BM, blockN = bn * BN;

  const int lane = t & 63;
  const int w = t >> 6;
  const int wr = w >> 1, wc = w & 1;
  const int lm = lane & 15, lg = lane >> 4;

  const int ktiles = K >> 5;

  // staging: 12 x 1KB global_load_lds per k-tile; wave w issues loads 3w..3w+2
  const _Float16* gp[3];
  int gstride[3];
  _Float16* ldst[3];
  #pragma unroll
  for (int i = 0; i < 3; ++i) {
    int l = w * 3 + i;
    if (l < 8) {
      gp[i] = Ap + ((size_t)bm * ktiles) * ATILE + l * 512 + lane * 8;
      gstride[i] = ATILE;
      ldst[i] = lds + l * 512;
    } else {
      gp[i] = Bp + ((size_t)bn * ktiles) * BTILE + (l - 8) * 512 + lane * 8;
      gstride[i] = BTILE;
      ldst[i] = lds + ATILE + (l - 8) * 512;
    }
  }

  // advancing-pointer STAGE: stages the tile gp currently points at, advances
#define STAGE_ADV(buf) {                                                       \
    _Pragma("unroll")                                                          \
    for (int i = 0; i < 3; ++i) {                                              \
      __builtin_amdgcn_global_load_lds((const void*)gp[i],                     \
                                       (void*)(ldst[i] + (buf) * BUFH),        \
                                       16, 0, 0);                              \
      gp[i] += gstride[i];                                                     \
    } }

  f32x4 acc[4][2];
  #pragma unroll
  for (int i = 0; i < 4; ++i)
    #pragma unroll
    for (int j = 0; j < 2; ++j) acc[i][j] = 0.0f;

  half4 nh0 = 0, nh1 = 0, nh2 = 0, nh3 = 0, nh4 = 0, nh5 = 0, nh6 = 0, nh7 = 0;

  // per-normal index base: group g covers rows gr0(g)=blockM+wr*64+(g&3)*16+lg*4
  // and col gc(g)=blockN+wc*32+(g>>2)*16+lm; idx = (gr0+j)*N + gc.
  const uint32_t nidx0 =
      (uint32_t)((blockM + wr * 64 + lg * 4) * N + blockN + wc * 32 + lm);

  const int nk = ktiles;               // 32 (G1) or 64 (G2)
  STAGE_ADV(0);
  __syncthreads();
  int cur = 0;

  for (int kt = 0; kt < nk; ++kt) {
    if (kt + 1 < nk) STAGE_ADV(cur ^ 1);

    const _Float16* base = lds + cur * BUFH;
    half8 fa[4], fb[2];
    #pragma unroll
    for (int fm = 0; fm < 4; ++fm)
      fa[fm] = *(const half8*)(base + lg * 1024 + (wr * 64 + fm * 16 + lm) * 8);
    #pragma unroll
    for (int fn = 0; fn < 2; ++fn)
      fb[fn] = *(const half8*)(base + ATILE + lg * 512 + (wc * 32 + fn * 16 + lm) * 8);
    #pragma unroll
    for (int fm = 0; fm < 4; ++fm)
      #pragma unroll
      for (int fn = 0; fn < 2; ++fn)
        acc[fm][fn] = __builtin_amdgcn_mfma_f32_16x16x32_f16(fa[fm], fb[fn], acc[fm][fn], 0, 0, 0);

    // in-loop RNG spread evenly: one 4-normal group when (kt & mask)==1.
    if ((kt & ((1 << RSHIFT) - 1)) == 1) {
      int g = kt >> RSHIFT;                 // 0..7, wave-uniform
      uint32_t gidx = nidx0 + (uint32_t)((g & 3) * 16 * N + (g >> 2) * 16);
      f32x4 v;
      #pragma unroll
      for (int j = 0; j < 4; ++j)
        v[j] = jax_normal(nk0, nk1, gidx + (uint32_t)(j * N));
      half4 hv;
      #pragma unroll
      for (int j = 0; j < 4; ++j) hv[j] = (_Float16)v[j];
      switch (g) {
        case 0: nh0 = hv; break;  case 1: nh1 = hv; break;
        case 2: nh2 = hv; break;  case 3: nh3 = hv; break;
        case 4: nh4 = hv; break;  case 5: nh5 = hv; break;
        case 6: nh6 = hv; break;  default: nh7 = hv; break;
      }
    }

    __syncthreads();                   // drains staging; LDS free after loop
    cur ^= 1;
  }

  // ---- epilogue ----
  const size_t obase1 = (((size_t)(bm * 32 + bn) * 4 + w) * 32) * 64 + lane;

#define EPI_STORE(fm_, fn_, NZV)                                               \
    _Pragma("unroll")                                                          \
    for (int j = 0; j < 4; ++j) {                                              \
      float v = tanh_fast(fmaf(oscale, acc[fm_][fn_][j], bv))                  \
                + NOISE_LEVEL * (float)NZV[j];                                 \
      if (OUTMODE == 0) {                                                      \
        int R = wr * 64 + (fm_) * 16 + lg * 4 + j;                             \
        int C = wc * 32 + (fn_) * 16 + lm;                                     \
        lds[R * 64 + (C ^ ((R & 7) << 3))] = (_Float16)v;                      \
      } else {                                                                 \
        outn[obase1 + (size_t)((fn_)*16 + (fm_)*4 + j) * 64] = (_Float16)v;    \
      }                                                                        \
      cp += fabsf(v);                                                          \
    }

#define EPI_FN(fn_, NZA, NZB, NZC, NZD) {                                      \
    const int gc = blockN + wc * 32 + (fn_)*16 + lm;                           \
    const float bv = bias[gc];                                                 \
    float cp = 0.0f;                                                           \
    EPI_STORE(0, fn_, NZA) EPI_STORE(1, fn_, NZB)                              \
    EPI_STORE(2, fn_, NZC) EPI_STORE(3, fn_, NZD)                              \
    cp += __shfl_xor(cp, 16);                                                  \
    cp += __shfl_xor(cp, 32);                                                  \
    if (lg == 0) atomicAdd(&colabs[gc], cp);                                   \
  }

  EPI_FN(0, nh0, nh1, nh2, nh3)
  EPI_FN(1, nh4, nh5, nh6, nh7)

  if (OUTMODE == 0) {
    // phase 2: coalesced packed-order stores. Block covers a1pk tiles
    // (rb=bm, kt = 2*bn + kh), kh in {0,1}; granule (kh,kq,row) -> 16B.
    __syncthreads();
    _Float16* dstb = outn + ((size_t)bm * 64 + 2 * bn) * 4096;
    #pragma unroll
    for (int pp = 0; pp < 4; ++pp) {
      int gidx = pp * 256 + t;                 // 0..1023
      int row = gidx & 127;
      int kq = (gidx >> 7) & 3;
      int kh = gidx >> 9;
      int cbase = kh * 32 + kq * 8;
      half8 hv = *(const half8*)&lds[row * 64 + (cbase ^ ((row & 7) << 3))];
      *(half8*)&dstb[(size_t)kh * 4096 + kq * 1024 + row * 8] = hv;
    }
  }
#undef EPI_FN
#undef EPI_STORE
#undef STAGE_ADV
}

// ---------------------------------------------------------------------------
// thermal = 0.7*prev + 0.3*(colabs*CROSSTALK); tn[i] = CROSSTALK * sum thermal[j]/(i-j)^2
// ---------------------------------------------------------------------------
__global__ __launch_bounds__(256)
void thermal_tn(const float* __restrict__ colabs, const float* __restrict__ prev_thermal,
                float* __restrict__ thermal_out, float* __restrict__ tn_out, int has_prev)
{
  __shared__ float th[2048];
  __shared__ float inv[2048];
  const int t = threadIdx.x;
  for (int j = t; j < 2048; j += 256) {
    float lt = colabs[j] * CROSSTALK;
    float pv = has_prev ? prev_thermal[j] : 0.0f;
    th[j] = 0.7f * pv + 0.3f * lt;
    float d = (float)j;
    inv[j] = (j == 0) ? 0.0f : 1.0f / (d * d);
  }
  __syncthreads();
  const int i = blockIdx.x * 256 + t;
  float s = 0.0f;
  #pragma unroll 4
  for (int j = 0; j < 2048; ++j) {
    int d = i - j; d = d < 0 ? -d : d;
    s += th[j] * inv[d];
  }
  tn_out[i] = s * CROSSTALK;
  thermal_out[i] = th[i];
}

// ---------------------------------------------------------------------------
// Final: out[b,:] = F_COH * (x2[b,:] @ Wout^T) + foldout  (coherence + thermal
// folded into scale/bias; no RNG). a2 is fragment-native fp16 (128x64 blocks).
// ---------------------------------------------------------------------------
__global__ __launch_bounds__(256)
void final_out(const _Float16* __restrict__ a2n, const float* __restrict__ Wout,
               const float* __restrict__ foldout, float* __restrict__ out)
{
  const int wave = threadIdx.x >> 6;
  const int lane = threadIdx.x & 63;
  const int b = blockIdx.x * 4 + wave;
  float acc0 = 0.0f, acc1 = 0.0f;
  #pragma unroll
  for (int i = 0; i < 8; ++i) {
    int h = lane * 4 + i * 256;
    half4 v4 = *(const half4*)&a2n[cnat_idx(b, h)];
    float4 w0 = *(const float4*)&Wout[h];
    float4 w1 = *(const float4*)&Wout[2048 + h];
    float xs[4]  = {(float)v4[0], (float)v4[1], (float)v4[2], (float)v4[3]};
    float w0s[4] = {w0.x, w0.y, w0.z, w0.w};
    float w1s[4] = {w1.x, w1.y, w1.z, w1.w};
    #pragma unroll
    for (int e = 0; e < 4; ++e) {
      acc0 = fmaf(xs[e], w0s[e], acc0);
      acc1 = fmaf(xs[e], w1s[e], acc1);
    }
  }
  #pragma unroll
  for (int off = 32; off > 0; off >>= 1) {
    acc0 += __shfl_down(acc0, off);
    acc1 += __shfl_down(acc1, off);
  }
  if (lane == 0) {
    out[(size_t)b * 2 + 0] = fmaf(F_COH, acc0, foldout[0]);
    out[(size_t)b * 2 + 1] = fmaf(F_COH, acc1, foldout[1]);
  }
}

extern "C" void kernel_launch(void* const* d_in, const int* in_sizes, int n_in,
                              void* d_out, int out_size, void* d_ws, size_t ws_size,
                              hipStream_t stream)
{
  (void)in_sizes; (void)n_in; (void)out_size; (void)ws_size;
  const float* x    = (const float*)d_in[0];
  const float* W1   = (const float*)d_in[1];
  const float* b1   = (const float*)d_in[2];
  const float* W2   = (const float*)d_in[3];
  const float* b2   = (const float*)d_in[4];
  const float* Wout = (const float*)d_in[5];
  const float* bout = (const float*)d_in[6];
  float* out = (float*)d_out;

  const int M = 8192, H = 2048, Din = 1024;
  const size_t MB = (size_t)1024 * 1024;

  char* ws = (char*)d_ws;
  // [0,32MB): a2 fragment-native fp16 (G2 out)
  _Float16* a2n = (_Float16*)ws;
  // [32,64MB): a1 in G2-A packed layout (G1 writes via LDS-transpose epilogue)
  _Float16* a1pk = (_Float16*)(ws + 32 * MB);
  // [64,80MB): xpk (G1 A = tanh(x), packed)
  _Float16* xpk = (_Float16*)(ws + 64 * MB);
  // [80,84MB): W1 packed; [84,92MB): W2 packed
  _Float16* W1p = (_Float16*)(ws + 80 * MB);
  _Float16* W2p = (_Float16*)(ws + 84 * MB);
  // [96MB,...): small arrays
  float* small = (float*)(ws + 96 * MB);
  float* colabs1  = small + 0 * H;
  float* colabs2  = small + 1 * H;
  float* thermal1 = small + 2 * H;
  float* thermal2 = small + 3 * H;
  float* tn1      = small + 4 * H;
  float* tn2      = small + 5 * H;
  float* foldb    = small + 6 * H;
  float* foldout  = small + 7 * H;

  // fold_in keys: key(42) = (0,42); fold_in(key, d) = threefry(key, [0,d]).
  uint32_t kn0a, kn0b, kn1a, kn1b;
  threefry2x32(0u, 42u, 0u, 0u, kn0a, kn0b);   // noise, layer 0
  threefry2x32(0u, 42u, 0u, 2u, kn1a, kn1b);   // noise, layer 1

  hipMemsetAsync(colabs1, 0, 2 * H * sizeof(float), stream);

  // one fused pack launch (W1, W2, tanh(x)) - coalesced-read mapping
  pack_all<<<2048, 256, 0, stream>>>(W1, W2, x, W1p, W2p, xpk);

  const int nblk = (M / BM) * (H / BN);   // 64*32 = 2048
  gemm_f16<0, 2><<<nblk, 256, 0, stream>>>(xpk, W1p, b1, a1pk, colabs1,
                                           M, H, Din, 1.0f, kn0a, kn0b);
  thermal_tn<<<H / 256, 256, 0, stream>>>(colabs1, nullptr, thermal1, tn1, 0);
  // foldb = b2 + F*(tn1 @ W2^T); G2 computes tanh(F*(a1@W2^T) + foldb) + noise
  bias_fold<<<H / 4, 256, 0, stream>>>(tn1, W2, b2, foldb, H, H, F_COH);
  gemm_f16<1, 3><<<nblk, 256, 0, stream>>>(a1pk, W2p, foldb, a2n, colabs2,
                                           M, H, H, F_COH, kn1a, kn1b);
  thermal_tn<<<H / 256, 256, 0, stream>>>(colabs2, thermal1, thermal2, tn2, 1);
  // foldout = bout + F*(tn2 @ Wout^T)
  bias_fold<<<1, 256, 0, stream>>>(tn2, Wout, bout, foldout, H, 2, F_COH);
  final_out<<<M / 4, 256, 0, stream>>>(a2n, Wout, foldout, out);
}